// Round 11
// baseline (568.250 us; speedup 1.0000x reference)
//
#include <hip/hip_runtime.h>

#define BB 16
#define NN 2048
#define MM 2048
#define EPSF 1e-9f
#define SKIPT (-135.0f)   // exp2(arg) == 0 below this

// Sweep kernels: 512 blocks x 1024 threads. Block = (batch, group of 128
// outputs, stream-half of 1024 elems). 16 waves share the 128 outputs
// (2 per lane); each wave streams a private 64-elem LDS segment. Partials
// LDS-reduced across waves -> 1 atomic per (output,value) per block.
// Ping-pong parity identical to R8/R9/R10 scheme.

// ---------------- init ----------------
__global__ __launch_bounds__(256) void init_kernel(
    const float* __restrict__ xyz1, const float* __restrict__ xyz2,
    float4* __restrict__ P1, float4* __restrict__ P2,
    float* __restrict__ remR0,
    float* __restrict__ stRS, float* __restrict__ stU,
    float* __restrict__ stS, float* __restrict__ stT,
    float* __restrict__ out)
{
    const int t = blockIdx.x * 256 + threadIdx.x;   // 0 .. BB*NN-1
    if (t < BB * NN) {
        P1[t] = make_float4(xyz1[3*t+0], xyz1[3*t+1], xyz1[3*t+2], 0.0f);
        stRS[t] = 0.0f; stRS[BB*NN + t] = 0.0f;
        stU[t]  = 0.0f; stU[BB*NN + t]  = 0.0f;
    }
    if (t < BB * MM) {
        P2[t] = make_float4(xyz2[3*t+0], xyz2[3*t+1], xyz2[3*t+2], 0.0f);
        remR0[t] = 1.0f;
        stS[t] = 0.0f; stS[BB*MM + t] = 0.0f;
        stT[t] = 0.0f; stT[BB*MM + t] = 0.0f;
    }
    if (t < BB) out[t] = 0.0f;
}

// ---------------- rowInit: stRS[1] += sum_l exp(coef0*d2) (remR=1) ----------------
__global__ __launch_bounds__(1024, 8) void rowInit(
    const float4* __restrict__ P1, const float4* __restrict__ P2,
    float* __restrict__ stRSacc, float coef)
{
    __shared__ float4 sCol[1024];                 // 16 KB
    __shared__ float2 red[16 * 64];               // 8 KB
    const int tid = threadIdx.x;
    const int lane = tid & 63;
    const int wave = tid >> 6;
    const int batch = blockIdx.x >> 5;
    const int rem   = blockIdx.x & 31;
    const int rg    = rem >> 1;                   // 128-row group 0..15
    const int half  = rem & 1;                    // stream half

    sCol[tid] = P2[batch * MM + half * 1024 + tid];
    __syncthreads();

    const int row0 = batch * NN + rg * 128 + lane;
    const float4 p0 = P1[row0];
    const float4 p1 = P1[row0 + 64];
    float rs0 = 0.0f, rs1 = 0.0f;
    const int base = wave * 64;
#pragma unroll 4
    for (int k = 0; k < 64; ++k) {
        const float4 q = sCol[base + k];
        float dx = p0.x - q.x, dy = p0.y - q.y, dz = p0.z - q.z;
        const float g0 = coef * (dx*dx + dy*dy + dz*dz);
        dx = p1.x - q.x; dy = p1.y - q.y; dz = p1.z - q.z;
        const float g1 = coef * (dx*dx + dy*dy + dz*dz);
        if (__ballot((g0 > SKIPT) || (g1 > SKIPT))) {
            rs0 += __builtin_amdgcn_exp2f(g0);
            rs1 += __builtin_amdgcn_exp2f(g1);
        }
    }
    red[wave * 64 + lane] = make_float2(rs0, rs1);
    __syncthreads();
    if (tid < 128) {
        const int l2 = tid >> 1, v = tid & 1;
        const float* rp = (const float*)red;
        float acc = 0.0f;
#pragma unroll
        for (int w = 0; w < 16; ++w) acc += rp[w * 128 + tid];
        atomicAdd(&stRSacc[batch * NN + rg * 128 + l2 + (v << 6)], acc);
    }
}

// ---------------- colK ----------------
// MODE 0: j==0 (remL=1). MODE 1: general. MODE 2: j==9 (coef==0 -> e=scale).
template<int MODE, bool SPARSE>
__global__ __launch_bounds__(1024, 8) void colK(
    const float4* __restrict__ P1, const float4* __restrict__ P2,
    const float* __restrict__ stRSr, const float* __restrict__ stUr,
    float* __restrict__ stRSz, float* __restrict__ stUz,
    const float* __restrict__ remLr, float* __restrict__ remLw,
    const float* __restrict__ scaler, float* __restrict__ scalew,
    float* __restrict__ stS, float* __restrict__ stT,
    float coef)
{
    __shared__ float4 sRow[1024];                 // 16 KB: x1,y1,z1,scale_j
    __shared__ float4 red[16 * 64];               // 16 KB
    const int tid = threadIdx.x;
    const int lane = tid & 63;
    const int wave = tid >> 6;
    const int batch = blockIdx.x >> 5;
    const int rem   = blockIdx.x & 31;
    const int cg    = rem >> 1;                   // 128-col group 0..15
    const int half  = rem & 1;                    // stream (row) half

    // prelude: finalize this block's 1024 stream rows (dup x16 cg; cg==0 stores)
    {
        const int gi = batch * NN + half * 1024 + tid;
        float L;
        if (MODE == 0) L = 1.0f;
        else           L = fmaxf(remLr[gi] - scaler[gi] * stUr[gi], 0.0f);
        const float sc = L / (stRSr[gi] + EPSF);
        const float4 p = P1[gi];
        sRow[tid] = make_float4(p.x, p.y, p.z, sc);
        if (cg == 0) {
            remLw[gi] = L;
            scalew[gi] = sc;
            stRSz[gi] = 0.0f; stUz[gi] = 0.0f;
        }
    }
    __syncthreads();

    const int col0 = batch * MM + cg * 128 + lane;
    const float4 q0 = P2[col0];
    const float4 q1 = P2[col0 + 64];
    float s0 = 0.0f, t0 = 0.0f, s1 = 0.0f, t1 = 0.0f;
    const int base = wave * 64;
#pragma unroll 4
    for (int k = 0; k < 64; ++k) {
        const float4 a = sRow[base + k];
        float dx = a.x - q0.x, dy = a.y - q0.y, dz = a.z - q0.z;
        const float d20 = dx*dx + dy*dy + dz*dz;
        dx = a.x - q1.x; dy = a.y - q1.y; dz = a.z - q1.z;
        const float d21 = dx*dx + dy*dy + dz*dz;
        if (SPARSE) {
            const float g0 = coef * d20, g1 = coef * d21;
            if (__ballot((g0 > SKIPT) || (g1 > SKIPT))) {
                const float e0 = a.w * __builtin_amdgcn_exp2f(g0);
                const float e1 = a.w * __builtin_amdgcn_exp2f(g1);
                s0 += e0; s1 += e1;
                t0 = fmaf(e0, __builtin_amdgcn_sqrtf(d20), t0);
                t1 = fmaf(e1, __builtin_amdgcn_sqrtf(d21), t1);
            }
        } else {
            const float e0 = (MODE == 2) ? a.w : a.w * __builtin_amdgcn_exp2f(coef * d20);
            const float e1 = (MODE == 2) ? a.w : a.w * __builtin_amdgcn_exp2f(coef * d21);
            s0 += e0; s1 += e1;
            t0 = fmaf(e0, __builtin_amdgcn_sqrtf(d20), t0);
            t1 = fmaf(e1, __builtin_amdgcn_sqrtf(d21), t1);
        }
    }
    red[wave * 64 + lane] = make_float4(s0, t0, s1, t1);
    __syncthreads();
    if (tid < 256) {
        const int l2 = tid >> 2, v = tid & 3;     // v: 0=s0 1=t0 2=s1 3=t1
        const float* rp = (const float*)red;
        float acc = 0.0f;
#pragma unroll
        for (int w = 0; w < 16; ++w) acc += rp[w * 256 + tid];
        const int c = batch * MM + cg * 128 + l2 + ((v >> 1) << 6);
        if (v & 1) atomicAdd(&stT[c], acc);
        else       atomicAdd(&stS[c], acc);
    }
}

// ---------------- rowK ----------------
// MODE 1: general. MODE 2: j==8 (rs = sum remR_9, u at coefP direct).
template<int MODE, bool SPARSE>
__global__ __launch_bounds__(1024, 8) void rowK(
    const float4* __restrict__ P1, const float4* __restrict__ P2,
    const float* __restrict__ stSr, const float* __restrict__ stTr,
    float* __restrict__ stSz, float* __restrict__ stTz,
    const float* __restrict__ remRr, float* __restrict__ remRw,
    float* __restrict__ stRS, float* __restrict__ stU,
    float* __restrict__ out,
    float coefP, float coefN)
{
    __shared__ float4 sCol[1024];                 // 16 KB: x2,y2,z2,remR_{j+1}
    __shared__ float  sPc[1024];                  // 4 KB: Pcol_j
    __shared__ float4 red[16 * 64];               // 16 KB
    const int tid = threadIdx.x;
    const int lane = tid & 63;
    const int wave = tid >> 6;
    const int batch = blockIdx.x >> 5;
    const int rem   = blockIdx.x & 31;
    const int rg    = rem >> 1;                   // 128-row group 0..15
    const int half  = rem & 1;                    // stream (col) half

    // prelude: finalize this block's 1024 stream cols (dup x16 rg; rg==0 stores)
    float cpart = 0.0f;
    {
        const int gl = batch * MM + half * 1024 + tid;
        const float R  = remRr[gl];
        const float s  = stSr[gl];
        const float t2 = stTr[gl];
        const float sumr = s * R;
        const float cons = fminf(R / (sumr + EPSF), 1.0f);
        const float pcol = R * cons;
        const float Rn   = fmaxf(R - sumr * cons, 0.0f);
        const float4 p = P2[gl];
        sCol[tid] = make_float4(p.x, p.y, p.z, Rn);
        sPc[tid]  = pcol;
        if (rg == 0) {
            remRw[gl] = Rn;
            stSz[gl] = 0.0f; stTz[gl] = 0.0f;
            cpart = pcol * t2;                    // cost contribution
        }
    }
    if (rg == 0) {
#pragma unroll
        for (int off = 32; off > 0; off >>= 1) cpart += __shfl_xor(cpart, off, 64);
        if (lane == 0) atomicAdd(out + batch, cpart);
    }
    __syncthreads();

    const int row0 = batch * NN + rg * 128 + lane;
    const float4 p0 = P1[row0];
    const float4 p1 = P1[row0 + 64];
    float rs0 = 0.0f, u0 = 0.0f, rs1 = 0.0f, u1 = 0.0f;
    const int base = wave * 64;
#pragma unroll 4
    for (int k = 0; k < 64; ++k) {
        const float4 q = sCol[base + k];
        const float pc = sPc[base + k];
        float dx = p0.x - q.x, dy = p0.y - q.y, dz = p0.z - q.z;
        const float d20 = dx*dx + dy*dy + dz*dz;
        dx = p1.x - q.x; dy = p1.y - q.y; dz = p1.z - q.z;
        const float d21 = dx*dx + dy*dy + dz*dz;
        if (MODE == 1) {
            if (SPARSE) {
                const float g0 = coefN * d20, g1 = coefN * d21;
                if (__ballot((g0 > SKIPT) || (g1 > SKIPT))) {
                    const float en0 = __builtin_amdgcn_exp2f(g0);
                    const float en1 = __builtin_amdgcn_exp2f(g1);
                    const float e20 = en0 * en0, e21 = en1 * en1;
                    u0  = fmaf(e20 * e20, pc, u0);    // e_prev = e_next^4
                    u1  = fmaf(e21 * e21, pc, u1);
                    rs0 = fmaf(en0, q.w, rs0);
                    rs1 = fmaf(en1, q.w, rs1);
                }
            } else {
                const float en0 = __builtin_amdgcn_exp2f(coefN * d20);
                const float en1 = __builtin_amdgcn_exp2f(coefN * d21);
                const float e20 = en0 * en0, e21 = en1 * en1;
                u0  = fmaf(e20 * e20, pc, u0);
                u1  = fmaf(e21 * e21, pc, u1);
                rs0 = fmaf(en0, q.w, rs0);
                rs1 = fmaf(en1, q.w, rs1);
            }
        } else {
            u0  = fmaf(__builtin_amdgcn_exp2f(coefP * d20), pc, u0);
            u1  = fmaf(__builtin_amdgcn_exp2f(coefP * d21), pc, u1);
            rs0 += q.w;                           // e_next = exp(0) = 1
            rs1 += q.w;
        }
    }
    red[wave * 64 + lane] = make_float4(rs0, u0, rs1, u1);
    __syncthreads();
    if (tid < 256) {
        const int l2 = tid >> 2, v = tid & 3;     // v: 0=rs0 1=u0 2=rs1 3=u1
        const float* rp = (const float*)red;
        float acc = 0.0f;
#pragma unroll
        for (int w = 0; w < 16; ++w) acc += rp[w * 256 + tid];
        const int r = batch * NN + rg * 128 + l2 + ((v >> 1) << 6);
        if (v & 1) atomicAdd(&stU[r], acc);
        else       atomicAdd(&stRS[r], acc);
    }
}

// ---------------- finCost: cost for level 9 ----------------
__global__ __launch_bounds__(256) void finCost(
    const float* __restrict__ stSr, const float* __restrict__ stTr,
    const float* __restrict__ remRr, float* __restrict__ out)
{
    const int idx = blockIdx.x * 256 + threadIdx.x;
    const int batch = idx / MM;
    const float R = remRr[idx];
    const float sumr = stSr[idx] * R;
    const float cons = fminf(R / (sumr + EPSF), 1.0f);
    float c = R * cons * stTr[idx];
#pragma unroll
    for (int off = 32; off > 0; off >>= 1) c += __shfl_xor(c, off, 64);
    if ((threadIdx.x & 63) == 0) atomicAdd(out + batch, c);
}

extern "C" void kernel_launch(void* const* d_in, const int* in_sizes, int n_in,
                              void* d_out, int out_size, void* d_ws, size_t ws_size,
                              hipStream_t stream)
{
    const float* xyz1 = (const float*)d_in[0];
    const float* xyz2 = (const float*)d_in[1];
    float* out = (float*)d_out;

    const int BN = BB * NN, BM = BB * MM;
    float4* P1 = (float4*)d_ws;
    float4* P2 = P1 + BN;
    float* remL  = (float*)(P2 + BM);       // [2][BN]
    float* scale = remL + 2 * BN;           // [2][BN]
    float* remR  = scale + 2 * BN;          // [2][BM]
    float* stRS  = remR + 2 * BM;           // [2][BN]
    float* stU   = stRS + 2 * BN;           // [2][BN]
    float* stS   = stU + 2 * BN;            // [2][BM]
    float* stT   = stS + 2 * BM;            // [2][BM]

    init_kernel<<<dim3(BN / 256), dim3(256), 0, stream>>>(
        xyz1, xyz2, P1, P2, remR, stRS, stU, stS, stT, out);

    // levels: j = 7..-1 -> -(4^j), then 0.  coef = level * log2(e)
    float coef[10];
    const double lv[10] = {-16384.0, -4096.0, -1024.0, -256.0, -64.0,
                           -16.0, -4.0, -1.0, -0.25, 0.0};
    for (int i = 0; i < 10; ++i) coef[i] = (float)(lv[i] * 1.4426950408889634);

    dim3 grid(BB * 32);                     // 512 blocks
    dim3 blk(1024);
    dim3 fgrid(BM / 256);                   // 128
    dim3 fblk(256);

    rowInit<<<grid, blk, 0, stream>>>(P1, P2, stRS + 1 * BN, coef[0]);

    for (int j = 0; j < 10; ++j) {
        const int p = j & 1, q = 1 - p;
        if (j == 0)
            colK<0, true><<<grid, blk, 0, stream>>>(P1, P2,
                stRS + q*BN, stU + q*BN, stRS + p*BN, stU + p*BN,
                remL + p*BN, remL + q*BN, scale + p*BN, scale + q*BN,
                stS + p*BM, stT + p*BM, coef[0]);
        else if (j <= 3)
            colK<1, true><<<grid, blk, 0, stream>>>(P1, P2,
                stRS + q*BN, stU + q*BN, stRS + p*BN, stU + p*BN,
                remL + p*BN, remL + q*BN, scale + p*BN, scale + q*BN,
                stS + p*BM, stT + p*BM, coef[j]);
        else if (j == 9)
            colK<2, false><<<grid, blk, 0, stream>>>(P1, P2,
                stRS + q*BN, stU + q*BN, stRS + p*BN, stU + p*BN,
                remL + p*BN, remL + q*BN, scale + p*BN, scale + q*BN,
                stS + p*BM, stT + p*BM, coef[9]);
        else
            colK<1, false><<<grid, blk, 0, stream>>>(P1, P2,
                stRS + q*BN, stU + q*BN, stRS + p*BN, stU + p*BN,
                remL + p*BN, remL + q*BN, scale + p*BN, scale + q*BN,
                stS + p*BM, stT + p*BM, coef[j]);

        if (j < 9) {
            if (j <= 2)
                rowK<1, true><<<grid, blk, 0, stream>>>(P1, P2,
                    stS + p*BM, stT + p*BM, stS + q*BM, stT + q*BM,
                    remR + p*BM, remR + q*BM,
                    stRS + p*BN, stU + p*BN, out, coef[j], coef[j+1]);
            else if (j < 8)
                rowK<1, false><<<grid, blk, 0, stream>>>(P1, P2,
                    stS + p*BM, stT + p*BM, stS + q*BM, stT + q*BM,
                    remR + p*BM, remR + q*BM,
                    stRS + p*BN, stU + p*BN, out, coef[j], coef[j+1]);
            else
                rowK<2, false><<<grid, blk, 0, stream>>>(P1, P2,
                    stS + p*BM, stT + p*BM, stS + q*BM, stT + q*BM,
                    remR + p*BM, remR + q*BM,
                    stRS + p*BN, stU + p*BN, out, coef[8], 0.0f);
        }
    }
    // level 9 cost: stS/stT parity 1, remR parity 1
    finCost<<<fgrid, fblk, 0, stream>>>(stS + 1*BM, stT + 1*BM, remR + 1*BM, out);
}

// Round 12
// 518.053 us; speedup vs baseline: 1.0969x; 1.0969x over previous
//
#include <hip/hip_runtime.h>

#define BB 16
#define NN 2048
#define MM 2048
#define EPSF 1e-9f
#define SKIPT (-135.0f)   // exp2(arg) == 0 below this

typedef float v2f __attribute__((ext_vector_type(2)));

constexpr int CH = 64;     // stream chunk length (2 outputs/thread)
// grid: BB batches x 4 groups(512 own-points) x 32 chunks = 2048 blocks
// Ping-pong parity identical to R8-R11 scheme.

// ---------------- init ----------------
__global__ __launch_bounds__(256) void init_kernel(
    const float* __restrict__ xyz1, const float* __restrict__ xyz2,
    float4* __restrict__ P1, float4* __restrict__ P2,
    float* __restrict__ remR0,
    float* __restrict__ stRS, float* __restrict__ stU,
    float* __restrict__ stS, float* __restrict__ stT,
    float* __restrict__ out)
{
    const int t = blockIdx.x * 256 + threadIdx.x;   // 0 .. BB*NN-1
    if (t < BB * NN) {
        P1[t] = make_float4(xyz1[3*t+0], xyz1[3*t+1], xyz1[3*t+2], 0.0f);
        stRS[t] = 0.0f; stRS[BB*NN + t] = 0.0f;
        stU[t]  = 0.0f; stU[BB*NN + t]  = 0.0f;
    }
    if (t < BB * MM) {
        P2[t] = make_float4(xyz2[3*t+0], xyz2[3*t+1], xyz2[3*t+2], 0.0f);
        remR0[t] = 1.0f;
        stS[t] = 0.0f; stS[BB*MM + t] = 0.0f;
        stT[t] = 0.0f; stT[BB*MM + t] = 0.0f;
    }
    if (t < BB) out[t] = 0.0f;
}

// ---------------- rowInit: stRS[1] += sum_l exp(coef0*d2) (remR=1) ----------------
__global__ __launch_bounds__(256) void rowInit(
    const float4* __restrict__ P1, const float4* __restrict__ P2,
    float* __restrict__ stRSacc, float coef)
{
    __shared__ float4 sCol[CH];
    const int chunks = MM / CH;                   // 32
    const int bpb = (NN / 512) * chunks;          // 128
    const int batch = blockIdx.x / bpb;
    const int rem   = blockIdx.x % bpb;
    const int rg    = rem / chunks;
    const int ic    = rem % chunks;
    const int t     = threadIdx.x;

    if (t < CH) sCol[t] = P2[batch * MM + ic * CH + t];
    __syncthreads();

    const int row0 = batch * NN + rg * 512 + t;
    const int row1 = row0 + 256;
    const float4 p0 = P1[row0];
    const float4 p1 = P1[row1];
    const v2f px = {p0.x, p1.x}, py = {p0.y, p1.y}, pz = {p0.z, p1.z};
    v2f rs = {0.0f, 0.0f};
#pragma unroll 4
    for (int ii = 0; ii < CH; ++ii) {
        const float4 q = sCol[ii];
        const v2f dx = px - q.x, dy = py - q.y, dz = pz - q.z;
        const v2f g = coef * (dx*dx + dy*dy + dz*dz);
        if (__ballot((g.x > SKIPT) || (g.y > SKIPT))) {
            v2f e;
            e.x = __builtin_amdgcn_exp2f(g.x);
            e.y = __builtin_amdgcn_exp2f(g.y);
            rs += e;
        }
    }
    atomicAdd(&stRSacc[row0], rs.x);
    atomicAdd(&stRSacc[row1], rs.y);
}

// ---------------- colK: row-finalize prelude + column-partial stream ----------------
// MODE 0: j==0 (remL=1). MODE 1: general. MODE 2: j==9 (coef==0 -> e=scale).
template<int MODE, bool SPARSE>
__global__ __launch_bounds__(256) void colK(
    const float4* __restrict__ P1, const float4* __restrict__ P2,
    const float* __restrict__ stRSr, const float* __restrict__ stUr,
    float* __restrict__ stRSz, float* __restrict__ stUz,
    const float* __restrict__ remLr, float* __restrict__ remLw,
    const float* __restrict__ scaler, float* __restrict__ scalew,
    float* __restrict__ stS, float* __restrict__ stT,
    float coef)
{
    __shared__ float4 sRow[CH];                   // x1,y1,z1,scale_j
    const int chunks = NN / CH;                   // 32
    const int bpb = (MM / 512) * chunks;          // 128
    const int batch = blockIdx.x / bpb;
    const int rem   = blockIdx.x % bpb;
    const int cg    = rem / chunks;
    const int ic    = rem % chunks;
    const int t     = threadIdx.x;

    // prelude: finalize rows of this chunk (duplicated by 4 cg-blocks; identical values)
    if (t < CH) {
        const int gi = batch * NN + ic * CH + t;
        float L;
        if (MODE == 0) L = 1.0f;
        else           L = fmaxf(remLr[gi] - scaler[gi] * stUr[gi], 0.0f);
        remLw[gi] = L;
        const float sc = L / (stRSr[gi] + EPSF);
        scalew[gi] = sc;
        const float4 p = P1[gi];
        sRow[t] = make_float4(p.x, p.y, p.z, sc);
        stRSz[gi] = 0.0f; stUz[gi] = 0.0f;        // zero next accumulation parity
    }
    __syncthreads();

    const int col0 = batch * MM + cg * 512 + t;
    const int col1 = col0 + 256;
    const float4 q0 = P2[col0];
    const float4 q1 = P2[col1];
    const v2f qx = {q0.x, q1.x}, qy = {q0.y, q1.y}, qz = {q0.z, q1.z};
    v2f s = {0.0f, 0.0f}, tt = {0.0f, 0.0f};
#pragma unroll 4
    for (int ii = 0; ii < CH; ++ii) {
        const float4 a = sRow[ii];
        const v2f dx = a.x - qx, dy = a.y - qy, dz = a.z - qz;
        const v2f d2 = dx*dx + dy*dy + dz*dz;
        if (SPARSE) {
            const v2f g = coef * d2;
            if (__ballot((g.x > SKIPT) || (g.y > SKIPT))) {
                v2f e;
                e.x = __builtin_amdgcn_exp2f(g.x);
                e.y = __builtin_amdgcn_exp2f(g.y);
                e *= a.w;
                v2f sq;
                sq.x = __builtin_amdgcn_sqrtf(d2.x);
                sq.y = __builtin_amdgcn_sqrtf(d2.y);
                s += e;
                tt += e * sq;
            }
        } else {
            v2f e;
            if (MODE == 2) { e.x = a.w; e.y = a.w; }
            else {
                const v2f g = coef * d2;
                e.x = a.w * __builtin_amdgcn_exp2f(g.x);
                e.y = a.w * __builtin_amdgcn_exp2f(g.y);
            }
            v2f sq;
            sq.x = __builtin_amdgcn_sqrtf(d2.x);
            sq.y = __builtin_amdgcn_sqrtf(d2.y);
            s += e;
            tt += e * sq;
        }
    }
    atomicAdd(&stS[col0], s.x);
    atomicAdd(&stT[col0], tt.x);
    atomicAdd(&stS[col1], s.y);
    atomicAdd(&stT[col1], tt.y);
}

// ---------------- rowK: col-finalize prelude + row-partial stream ----------------
// MODE 1: general. MODE 2: j==8 (rs = sum remR_9, u at coefP direct).
template<int MODE, bool SPARSE>
__global__ __launch_bounds__(256) void rowK(
    const float4* __restrict__ P1, const float4* __restrict__ P2,
    const float* __restrict__ stSr, const float* __restrict__ stTr,
    float* __restrict__ stSz, float* __restrict__ stTz,
    const float* __restrict__ remRr, float* __restrict__ remRw,
    float* __restrict__ stRS, float* __restrict__ stU,
    float* __restrict__ out,
    float coefP, float coefN)
{
    __shared__ float4 sCol[CH];                   // x2,y2,z2,remR_{j+1}
    __shared__ float  sPc[CH];                    // Pcol_j
    const int chunks = MM / CH;                   // 32
    const int bpb = (NN / 512) * chunks;          // 128
    const int batch = blockIdx.x / bpb;
    const int rem   = blockIdx.x % bpb;
    const int rg    = rem / chunks;
    const int ic    = rem % chunks;
    const int t     = threadIdx.x;

    // prelude: finalize cols of this chunk (duplicated by 4 rg-blocks; identical values)
    float c = 0.0f;
    if (t < CH) {
        const int gl = batch * MM + ic * CH + t;
        const float R  = remRr[gl];
        const float s  = stSr[gl];
        const float t2 = stTr[gl];
        const float sumr = s * R;
        const float cons = fminf(R / (sumr + EPSF), 1.0f);
        const float pcol = R * cons;
        const float Rn   = fmaxf(R - sumr * cons, 0.0f);
        remRw[gl] = Rn;
        const float4 p = P2[gl];
        sCol[t] = make_float4(p.x, p.y, p.z, Rn);
        sPc[t]  = pcol;
        stSz[gl] = 0.0f; stTz[gl] = 0.0f;         // zero next accumulation parity
        if (rg == 0) c = pcol * t2;               // cost contribution (once per chunk)
    }
    if (rg == 0) {
#pragma unroll
        for (int off = 32; off > 0; off >>= 1) c += __shfl_xor(c, off, 64);
        if (t < CH && (t & 63) == 0) atomicAdd(out + batch, c);
    }
    __syncthreads();

    const int row0 = batch * NN + rg * 512 + t;
    const int row1 = row0 + 256;
    const float4 p0 = P1[row0];
    const float4 p1 = P1[row1];
    const v2f px = {p0.x, p1.x}, py = {p0.y, p1.y}, pz = {p0.z, p1.z};
    v2f rs = {0.0f, 0.0f}, u = {0.0f, 0.0f};
#pragma unroll 4
    for (int ii = 0; ii < CH; ++ii) {
        const float4 q = sCol[ii];
        const float pc = sPc[ii];
        const v2f dx = px - q.x, dy = py - q.y, dz = pz - q.z;
        const v2f d2 = dx*dx + dy*dy + dz*dz;
        if (MODE == 1) {
            const v2f g = coefN * d2;
            if (SPARSE) {
                if (__ballot((g.x > SKIPT) || (g.y > SKIPT))) {
                    v2f en;
                    en.x = __builtin_amdgcn_exp2f(g.x);
                    en.y = __builtin_amdgcn_exp2f(g.y);
                    const v2f e2 = en * en;
                    const v2f e4 = e2 * e2;
                    u  += e4 * pc;                // e_prev = e_next^4
                    rs += en * q.w;
                }
            } else {
                v2f en;
                en.x = __builtin_amdgcn_exp2f(g.x);
                en.y = __builtin_amdgcn_exp2f(g.y);
                const v2f e2 = en * en;
                const v2f e4 = e2 * e2;
                u  += e4 * pc;
                rs += en * q.w;
            }
        } else {
            const v2f g = coefP * d2;
            v2f ep;
            ep.x = __builtin_amdgcn_exp2f(g.x);
            ep.y = __builtin_amdgcn_exp2f(g.y);
            u  += ep * pc;
            rs += q.w;                            // e_next = exp(0) = 1
        }
    }
    atomicAdd(&stRS[row0], rs.x);
    atomicAdd(&stU[row0], u.x);
    atomicAdd(&stRS[row1], rs.y);
    atomicAdd(&stU[row1], u.y);
}

// ---------------- finCost: cost for level 9 (no state updates) ----------------
__global__ __launch_bounds__(256) void finCost(
    const float* __restrict__ stSr, const float* __restrict__ stTr,
    const float* __restrict__ remRr, float* __restrict__ out)
{
    const int idx = blockIdx.x * 256 + threadIdx.x;
    const int batch = idx / MM;
    const float R = remRr[idx];
    const float sumr = stSr[idx] * R;
    const float cons = fminf(R / (sumr + EPSF), 1.0f);
    float c = R * cons * stTr[idx];
#pragma unroll
    for (int off = 32; off > 0; off >>= 1) c += __shfl_xor(c, off, 64);
    if ((threadIdx.x & 63) == 0) atomicAdd(out + batch, c);
}

extern "C" void kernel_launch(void* const* d_in, const int* in_sizes, int n_in,
                              void* d_out, int out_size, void* d_ws, size_t ws_size,
                              hipStream_t stream)
{
    const float* xyz1 = (const float*)d_in[0];
    const float* xyz2 = (const float*)d_in[1];
    float* out = (float*)d_out;

    const int BN = BB * NN, BM = BB * MM;
    float4* P1 = (float4*)d_ws;
    float4* P2 = P1 + BN;
    float* remL  = (float*)(P2 + BM);       // [2][BN]
    float* scale = remL + 2 * BN;           // [2][BN]
    float* remR  = scale + 2 * BN;          // [2][BM]
    float* stRS  = remR + 2 * BM;           // [2][BN]
    float* stU   = stRS + 2 * BN;           // [2][BN]
    float* stS   = stU + 2 * BN;            // [2][BM]
    float* stT   = stS + 2 * BM;            // [2][BM]

    init_kernel<<<dim3(BN / 256), dim3(256), 0, stream>>>(
        xyz1, xyz2, P1, P2, remR, stRS, stU, stS, stT, out);

    // levels: j = 7..-1 -> -(4^j), then 0.  coef = level * log2(e)
    float coef[10];
    const double lv[10] = {-16384.0, -4096.0, -1024.0, -256.0, -64.0,
                           -16.0, -4.0, -1.0, -0.25, 0.0};
    for (int i = 0; i < 10; ++i) coef[i] = (float)(lv[i] * 1.4426950408889634);

    dim3 grid(BB * 4 * (NN / CH));          // 16*4*32 = 2048
    dim3 fgrid(BM / 256);                   // 128
    dim3 blk(256);

    rowInit<<<grid, blk, 0, stream>>>(P1, P2, stRS + 1 * BN, coef[0]);

    for (int j = 0; j < 10; ++j) {
        const int p = j & 1, q = 1 - p;
        if (j == 0)
            colK<0, true><<<grid, blk, 0, stream>>>(P1, P2,
                stRS + q*BN, stU + q*BN, stRS + p*BN, stU + p*BN,
                remL + p*BN, remL + q*BN, scale + p*BN, scale + q*BN,
                stS + p*BM, stT + p*BM, coef[0]);
        else if (j <= 3)
            colK<1, true><<<grid, blk, 0, stream>>>(P1, P2,
                stRS + q*BN, stU + q*BN, stRS + p*BN, stU + p*BN,
                remL + p*BN, remL + q*BN, scale + p*BN, scale + q*BN,
                stS + p*BM, stT + p*BM, coef[j]);
        else if (j == 9)
            colK<2, false><<<grid, blk, 0, stream>>>(P1, P2,
                stRS + q*BN, stU + q*BN, stRS + p*BN, stU + p*BN,
                remL + p*BN, remL + q*BN, scale + p*BN, scale + q*BN,
                stS + p*BM, stT + p*BM, coef[9]);
        else
            colK<1, false><<<grid, blk, 0, stream>>>(P1, P2,
                stRS + q*BN, stU + q*BN, stRS + p*BN, stU + p*BN,
                remL + p*BN, remL + q*BN, scale + p*BN, scale + q*BN,
                stS + p*BM, stT + p*BM, coef[j]);

        if (j < 9) {
            if (j <= 2)
                rowK<1, true><<<grid, blk, 0, stream>>>(P1, P2,
                    stS + p*BM, stT + p*BM, stS + q*BM, stT + q*BM,
                    remR + p*BM, remR + q*BM,
                    stRS + p*BN, stU + p*BN, out, coef[j], coef[j+1]);
            else if (j < 8)
                rowK<1, false><<<grid, blk, 0, stream>>>(P1, P2,
                    stS + p*BM, stT + p*BM, stS + q*BM, stT + q*BM,
                    remR + p*BM, remR + q*BM,
                    stRS + p*BN, stU + p*BN, out, coef[j], coef[j+1]);
            else
                rowK<2, false><<<grid, blk, 0, stream>>>(P1, P2,
                    stS + p*BM, stT + p*BM, stS + q*BM, stT + q*BM,
                    remR + p*BM, remR + q*BM,
                    stRS + p*BN, stU + p*BN, out, coef[8], 0.0f);
        }
    }
    // level 9 cost: stS/stT parity 1, remR parity 1
    finCost<<<fgrid, blk, 0, stream>>>(stS + 1*BM, stT + 1*BM, remR + 1*BM, out);
}